// Round 13
// baseline (94.487 us; speedup 1.0000x reference)
//
#include <hip/hip_runtime.h>

using short8 = __attribute__((ext_vector_type(8))) short;
using f32x4  = __attribute__((ext_vector_type(4))) float;
using u32x4  = __attribute__((ext_vector_type(4))) unsigned int;

#define NC 256
#define NW 64
#define ND 21
#define HW 3072              /* 48*64, per-channel stride in floats */
#define H2 24

static const size_t WS_FULL  = (size_t)768 * 32 * 1024;              /* 24 MiB blobs */
static const size_t SCRATCH_OFF = (size_t)32 << 20;                  /* scratch @ 32 MiB */
static const size_t WS_PROBE = SCRATCH_OFF + (size_t)8 * 441 * HW * 4;  /* + 43.4 MB */

__device__ __forceinline__ int imax(int a, int b) { return a > b ? a : b; }
__device__ __forceinline__ int imin(int a, int b) { return a < b ? a : b; }

__device__ __forceinline__ unsigned int cvtpk(float a, float b) {
    unsigned int r;
    asm("v_cvt_pk_bf16_f32 %0, %1, %2" : "=v"(r) : "v"(a), "v"(b));
    return r;
}

// barrier draining LDS ops only — global loads/stores stay in flight
#define BARRIER() asm volatile("s_waitcnt lgkmcnt(0)\n\ts_barrier" ::: "memory")

// ============================================================================
// FRAGMENT-ORDERED blobs (32 KB per (src,b,y) row) — verified R11/R12.
// frag kk of wave (px,half) at [blob + kk*4096 + px*2048 + half*1024 + lane*16]
// ============================================================================

struct Stage { float2 v[16]; };   // one f32 row slice: 128 B/thread

__device__ __forceinline__ void stage_issue(Stage& st, const float* rowbase, int xp, int cg) {
    const float* s = rowbase + 2 * xp;
    #pragma unroll
    for (int cc = 0; cc < 2; ++cc)
        #pragma unroll
        for (int e = 0; e < 4; ++e) {
            int c = cc * 128 + cg * 8 + 2 * e;
            st.v[cc * 8 + 2 * e    ] = *reinterpret_cast<const float2*>(s + (size_t)c * HW);
            st.v[cc * 8 + 2 * e + 1] = *reinterpret_cast<const float2*>(s + (size_t)(c + 1) * HW);
        }
}

__device__ __forceinline__ void stage_pack(const Stage& st, int cc, u32x4& p0, u32x4& p1) {
    #pragma unroll
    for (int e = 0; e < 4; ++e) {
        float2 va = st.v[cc * 8 + 2 * e];
        float2 vb = st.v[cc * 8 + 2 * e + 1];
        p0[e] = cvtpk(va.x, vb.x);
        p1[e] = cvtpk(va.y, vb.y);
    }
}

// ---- pre-pass (IDENTICAL to R11/R12): f32 -> fragment-ordered blobs ----
__global__ __launch_bounds__(512, 4) void prep_kernel(const float* __restrict__ f1,
                                                      const float* __restrict__ f2,
                                                      unsigned short* __restrict__ ws) {
    int bid = blockIdx.x;
    int xcd = bid & 7;
    int m   = bid >> 3;            // [0,96)
    const float* src;
    int rid, blob_id;
    if (m < 48) { rid = xcd * 48 + m;        blob_id = rid;       src = f2; }
    else        { rid = xcd * 48 + (m - 48); blob_id = 384 + rid; src = f1; }
    int b = rid / 48, y = rid - b * 48;
    const float* row = src + (size_t)b * NC * HW + (size_t)y * NW;
    char* blob = reinterpret_cast<char*>(ws + ((size_t)blob_id << 14));

    int tid = threadIdx.x, xp = tid & 31, cg = tid >> 5;
    int half = xp >> 4, l15 = xp & 15, g4 = cg & 3;

    Stage st;
    stage_issue(st, row, xp, cg);

    #pragma unroll
    for (int cc = 0; cc < 2; ++cc) {
        u32x4 p0, p1;
        stage_pack(st, cc, p0, p1);
        int kk = cc * 4 + (cg >> 2);
        char* base = blob + kk * 4096 + half * 1024 + g4 * 256 + l15 * 16;
        *reinterpret_cast<u32x4*>(base)        = p0;   // px = 0
        *reinterpret_cast<u32x4*>(base + 2048) = p1;   // px = 1
    }
}

// ---- ABLATION PROBE: R11 main5 structure, store behavior templated ----
// STORE=0: full compute, global stores elided (values kept live via asm).
// STORE=1: stores to dst (dst = ws-scratch OR the real out buffer).
template<int STORE>
__global__ __launch_bounds__(512, 4) void corr_probe(const unsigned short* __restrict__ ws,
                                                     float* __restrict__ dst) {
    __shared__ float Sl[2][64 * 32];                      // 2 x 8 KB, additive-swizzled

    int bid = blockIdx.x;
    // bijective XCD swizzle: 768 = 8*96; XCD k serves batch b=k only
    int swz = (bid & 7) * 96 + (bid >> 3);
    int hf  = swz & 1;
    int uy  = (swz >> 1) % 24;
    int g   = swz / 48;            // b*2 + py
    int py  = g & 1, b = g >> 1;
    int y   = 2 * uy + py;

    int tid = threadIdx.x, lane = tid & 63, w = tid >> 6;
    int px = w & 1, mh = (w >> 1) & 1, nh = (w >> 2) & 1;
    int l15 = lane & 15, g4 = lane >> 4;

    float* outb = dst + (size_t)b * 441 * HW + (size_t)y * NW;   // + d*HW + x

    int ilo_h = hf ? 11 : 0, ihi_h = hf ? 20 : 10;
    int ilo   = imax(ilo_h, 10 - uy);
    int ihi   = imin(ihi_h, 33 - uy);

    // zero-fill output rows whose displaced source row is out of bounds
    if (STORE) {
        for (int i = ilo_h; i <= ihi_h; ++i) {
            if (i >= ilo && i <= ihi) continue;
            for (int t = tid; t < ND * 64; t += 512) {
                int j = t >> 6, x = t & 63;
                outb[(size_t)(i * ND + j) * HW + x] = 0.f;
            }
        }
    }
    if (ilo > ihi) return;

    // ---- A fragments: coalesced, one-time ----
    const char* ablob = reinterpret_cast<const char*>(ws + ((size_t)(384 + b * 48 + y) << 14));
    int aoff = px * 2048 + mh * 1024 + lane * 16;
    short8 afrag[8];
    #pragma unroll
    for (int kk = 0; kk < 8; ++kk)
        afrag[kk] = *reinterpret_cast<const short8*>(ablob + kk * 4096 + aoff);

    int boff = px * 2048 + nh * 1024 + lane * 16;
    auto loadB = [&](short8* bf, int i) {
        const char* bb = reinterpret_cast<const char*>(
            ws + ((size_t)(b * 48 + 2 * (uy + i - 10) + py) << 14));
        #pragma unroll
        for (int kk = 0; kk < 8; ++kk)
            bf[kk] = *reinterpret_cast<const short8*>(bb + kk * 4096 + boff);
    };

    int srow = 2 * (mh * 16 + g4 * 4) + px;      // + 2*rr
    int scol = nh * 16 + l15;
    int x  = tid & 63;
    int j0 = tid >> 6;                            // j slots: j0, j0+8, j0+16

    short8 bfA[8], bfB[8];
    loadB(bfA, ilo);
    if (ilo + 1 <= ihi) loadB(bfB, ilo + 1);

    int i = ilo;
    while (true) {
        { // ---- phase A: bfA, Sl[0] ----
            f32x4 acc = {0.f, 0.f, 0.f, 0.f};
            #pragma unroll
            for (int kk = 0; kk < 8; ++kk)
                acc = __builtin_amdgcn_mfma_f32_16x16x32_bf16(afrag[kk], bfA[kk], acc, 0, 0, 0);
            if (i + 2 <= ihi) loadB(bfA, i + 2);
            #pragma unroll
            for (int rr = 0; rr < 4; ++rr) {
                int row = srow + 2 * rr;
                Sl[0][(row << 5) | ((scol + row) & 31)] = acc[rr] * (1.f / 256.f);
            }
            BARRIER();
            float* oi = outb + (size_t)i * (ND * HW);
            #pragma unroll
            for (int s = 0; s < 3; ++s) {
                int j = j0 + 8 * s;
                if (j < ND) {
                    int vx = (x >> 1) + j - 10;
                    float v = ((unsigned)vx < 32u) ? Sl[0][(x << 5) | ((vx + x) & 31)] : 0.f;
                    if (STORE) oi[(size_t)j * HW + x] = v;
                    else       asm volatile("" :: "v"(v));   // keep live, no DCE
                }
            }
            if (++i > ihi) break;
        }
        { // ---- phase B: bfB, Sl[1] ----
            f32x4 acc = {0.f, 0.f, 0.f, 0.f};
            #pragma unroll
            for (int kk = 0; kk < 8; ++kk)
                acc = __builtin_amdgcn_mfma_f32_16x16x32_bf16(afrag[kk], bfB[kk], acc, 0, 0, 0);
            if (i + 2 <= ihi) loadB(bfB, i + 2);
            #pragma unroll
            for (int rr = 0; rr < 4; ++rr) {
                int row = srow + 2 * rr;
                Sl[1][(row << 5) | ((scol + row) & 31)] = acc[rr] * (1.f / 256.f);
            }
            BARRIER();
            float* oi = outb + (size_t)i * (ND * HW);
            #pragma unroll
            for (int s = 0; s < 3; ++s) {
                int j = j0 + 8 * s;
                if (j < ND) {
                    int vx = (x >> 1) + j - 10;
                    float v = ((unsigned)vx < 32u) ? Sl[1][(x << 5) | ((vx + x) & 31)] : 0.f;
                    if (STORE) oi[(size_t)j * HW + x] = v;
                    else       asm volatile("" :: "v"(v));
                }
            }
            if (++i > ihi) break;
        }
    }
}

// ============================================================================
// fallback (round-1 structure, known good, no workspace)
// ============================================================================
__device__ __forceinline__ unsigned int swz_off(int row, int cb) {
    return (row << 9) + ((cb << 1) ^ (((row >> 1) & 7) << 4));
}

__device__ __forceinline__ void stage_commit_lds(const Stage& st, unsigned short* lds, int xp, int cg) {
    #pragma unroll
    for (int cc = 0; cc < 2; ++cc) {
        int c0 = cc * 128 + cg * 8;
        u32x4 p0, p1;
        stage_pack(st, cc, p0, p1);
        *reinterpret_cast<u32x4*>(reinterpret_cast<char*>(lds) + swz_off(2 * xp,     c0)) = p0;
        *reinterpret_cast<u32x4*>(reinterpret_cast<char*>(lds) + swz_off(2 * xp + 1, c0)) = p1;
    }
}

__global__ __launch_bounds__(512, 4) void corr_fallback(const float* __restrict__ f1,
                                                        const float* __restrict__ f2,
                                                        float* __restrict__ out) {
    __shared__ __align__(16) unsigned short Alds[64 * 256];
    __shared__ __align__(16) unsigned short Blds[64 * 256];
    __shared__ float Slds[64][33];

    int bid = blockIdx.x;
    int swz = (bid & 7) * 48 + (bid >> 3);
    int uy = swz % 24;
    int g  = swz / 24;
    int py = g & 1;
    int b  = g >> 1;
    int y  = 2 * uy + py;

    int tid = threadIdx.x, lane = tid & 63, w = tid >> 6;
    int xp = tid & 31, cg = tid >> 5;

    const float* f1row  = f1 + (size_t)b * NC * HW + (size_t)y * NW;
    const float* f2base = f2 + (size_t)b * NC * HW;
    float* outb = out + (size_t)b * 441 * HW + (size_t)y * NW;

    for (int i = 0; i < ND; ++i) {
        int vy = uy + i - 10;
        if (vy >= 0 && vy < H2) continue;
        for (int t = tid; t < ND * 64; t += 512) {
            int j = t >> 6, x = t & 63;
            outb[(size_t)(i * ND + j) * HW + x] = 0.f;
        }
    }

    Stage st;
    stage_issue(st, f1row, xp, cg);
    stage_commit_lds(st, Alds, xp, cg);
    __syncthreads();

    int px  = w & 1;
    int m0  = ((w >> 1) & 1) * 16;
    int n0  = ((w >> 2) & 1) * 16;
    int l15 = lane & 15;
    int kgr = (lane >> 4) * 8;

    short8 afrag[8];
    int arow = 2 * (m0 + l15) + px;
    #pragma unroll
    for (int kk = 0; kk < 8; ++kk)
        afrag[kk] = *reinterpret_cast<const short8*>(
            reinterpret_cast<const char*>(Alds) + swz_off(arow, kk * 32 + kgr));

    int brow = 2 * (n0 + l15) + px;
    int srow = 2 * (m0 + (lane >> 4) * 4) + px;
    int scol = n0 + l15;

    for (int vy = uy - 10; vy <= uy + 10; ++vy) {
        if (vy < 0 || vy >= H2) continue;
        int i  = vy - uy + 10;
        int y2 = 2 * vy + py;
        __syncthreads();
        stage_issue(st, f2base + (size_t)y2 * NW, xp, cg);
        stage_commit_lds(st, Blds, xp, cg);
        __syncthreads();

        f32x4 acc = {0.f, 0.f, 0.f, 0.f};
        #pragma unroll
        for (int kk = 0; kk < 8; ++kk) {
            short8 bfrag = *reinterpret_cast<const short8*>(
                reinterpret_cast<const char*>(Blds) + swz_off(brow, kk * 32 + kgr));
            acc = __builtin_amdgcn_mfma_f32_16x16x32_bf16(afrag[kk], bfrag, acc, 0, 0, 0);
        }
        #pragma unroll
        for (int r = 0; r < 4; ++r)
            Slds[srow + 2 * r][scol] = acc[r] * (1.f / 256.f);
        __syncthreads();

        for (int t = tid; t < ND * 64; t += 512) {
            int j = t >> 6, x = t & 63;
            int vx = (x >> 1) + j - 10;
            float v = ((unsigned)vx < 32u) ? Slds[x][vx] : 0.f;
            outb[(size_t)(i * ND + j) * HW + x] = v;
        }
    }
}

extern "C" void kernel_launch(void* const* d_in, const int* in_sizes, int n_in,
                              void* d_out, int out_size, void* d_ws, size_t ws_size,
                              hipStream_t stream) {
    const float* in1 = (const float*)d_in[0];
    const float* in2 = (const float*)d_in[1];
    float* o = (float*)d_out;
    unsigned short* ws = (unsigned short*)d_ws;
    if (ws_size >= WS_PROBE) {
        float* scratch = (float*)((char*)d_ws + SCRATCH_OFF);
        hipLaunchKernelGGL(prep_kernel, dim3(768), dim3(512), 0, stream, in1, in2, ws);
        // ablation probes (rocprof separates the dispatches):
        hipLaunchKernelGGL(corr_probe<0>, dim3(768), dim3(512), 0, stream, ws, scratch); // no stores
        hipLaunchKernelGGL(corr_probe<1>, dim3(768), dim3(512), 0, stream, ws, scratch); // stores -> ws
        // the real output (last, correct):
        hipLaunchKernelGGL(corr_probe<1>, dim3(768), dim3(512), 0, stream, ws, o);       // stores -> out
    } else if (ws_size >= WS_FULL) {
        hipLaunchKernelGGL(prep_kernel, dim3(768), dim3(512), 0, stream, in1, in2, ws);
        hipLaunchKernelGGL(corr_probe<1>, dim3(768), dim3(512), 0, stream, ws, o);
    } else {
        hipLaunchKernelGGL(corr_fallback, dim3(384), dim3(512), 0, stream, in1, in2, o);
    }
}

// Round 14
// 43.582 us; speedup vs baseline: 2.1680x; 2.1680x over previous
//
#include <hip/hip_runtime.h>

using short8 = __attribute__((ext_vector_type(8))) short;
using f32x4  = __attribute__((ext_vector_type(4))) float;
using u32x4  = __attribute__((ext_vector_type(4))) unsigned int;

#define NC 256
#define NW 64
#define ND 21
#define HW 3072              /* 48*64, per-channel stride in floats */
#define H2 24

static const size_t WS_FULL = (size_t)768 * 32 * 1024;   /* f2 + f1 blobs */

__device__ __forceinline__ int imax(int a, int b) { return a > b ? a : b; }
__device__ __forceinline__ int imin(int a, int b) { return a < b ? a : b; }

__device__ __forceinline__ unsigned int cvtpk(float a, float b) {
    unsigned int r;
    asm("v_cvt_pk_bf16_f32 %0, %1, %2" : "=v"(r) : "v"(a), "v"(b));
    return r;
}

// barrier draining LDS ops only — global loads/stores stay in flight
#define BARRIER() asm volatile("s_waitcnt lgkmcnt(0)\n\ts_barrier" ::: "memory")

// ============================================================================
// FRAGMENT-ORDERED blobs (32 KB per (src,b,y) row) — verified R11-R13.
// frag kk of wave (px,half) at [blob + kk*4096 + px*2048 + half*1024 + lane*16]
// ============================================================================

struct Stage { float2 v[16]; };   // one f32 row slice: 128 B/thread

__device__ __forceinline__ void stage_issue(Stage& st, const float* rowbase, int xp, int cg) {
    const float* s = rowbase + 2 * xp;
    #pragma unroll
    for (int cc = 0; cc < 2; ++cc)
        #pragma unroll
        for (int e = 0; e < 4; ++e) {
            int c = cc * 128 + cg * 8 + 2 * e;
            st.v[cc * 8 + 2 * e    ] = *reinterpret_cast<const float2*>(s + (size_t)c * HW);
            st.v[cc * 8 + 2 * e + 1] = *reinterpret_cast<const float2*>(s + (size_t)(c + 1) * HW);
        }
}

__device__ __forceinline__ void stage_pack(const Stage& st, int cc, u32x4& p0, u32x4& p1) {
    #pragma unroll
    for (int e = 0; e < 4; ++e) {
        float2 va = st.v[cc * 8 + 2 * e];
        float2 vb = st.v[cc * 8 + 2 * e + 1];
        p0[e] = cvtpk(va.x, vb.x);
        p1[e] = cvtpk(va.y, vb.y);
    }
}

// ---- pre-pass (IDENTICAL to R11-R13): f32 -> fragment-ordered blobs ----
__global__ __launch_bounds__(512, 4) void prep_kernel(const float* __restrict__ f1,
                                                      const float* __restrict__ f2,
                                                      unsigned short* __restrict__ ws) {
    int bid = blockIdx.x;
    int xcd = bid & 7;
    int m   = bid >> 3;            // [0,96)
    const float* src;
    int rid, blob_id;
    if (m < 48) { rid = xcd * 48 + m;        blob_id = rid;       src = f2; }
    else        { rid = xcd * 48 + (m - 48); blob_id = 384 + rid; src = f1; }
    int b = rid / 48, y = rid - b * 48;
    const float* row = src + (size_t)b * NC * HW + (size_t)y * NW;
    char* blob = reinterpret_cast<char*>(ws + ((size_t)blob_id << 14));

    int tid = threadIdx.x, xp = tid & 31, cg = tid >> 5;
    int half = xp >> 4, l15 = xp & 15, g4 = cg & 3;

    Stage st;
    stage_issue(st, row, xp, cg);

    #pragma unroll
    for (int cc = 0; cc < 2; ++cc) {
        u32x4 p0, p1;
        stage_pack(st, cc, p0, p1);
        int kk = cc * 4 + (cg >> 2);
        char* base = blob + kk * 4096 + half * 1024 + g4 * 256 + l15 * 16;
        *reinterpret_cast<u32x4*>(base)        = p0;   // px = 0
        *reinterpret_cast<u32x4*>(base + 2048) = p1;   // px = 1
    }
}

// ---- main kernel v7 = verified R11/R13 structure + FLOAT4 STORES ----
// R13 probes: stores add ~15 us (2.9 TB/s marginal) independent of dest;
// fillBuffer (16 B/lane dwordx4) hits 6.7 TB/s -> widen our stores to 16 B/lane.
__global__ __launch_bounds__(512, 4) void corr_main7(const unsigned short* __restrict__ ws,
                                                     float* __restrict__ out) {
    __shared__ float Sl[2][64 * 32];                      // 2 x 8 KB, additive-swizzled

    int bid = blockIdx.x;
    // bijective XCD swizzle: 768 = 8*96; XCD k serves batch b=k only
    int swz = (bid & 7) * 96 + (bid >> 3);
    int hf  = swz & 1;
    int uy  = (swz >> 1) % 24;
    int g   = swz / 48;            // b*2 + py
    int py  = g & 1, b = g >> 1;
    int y   = 2 * uy + py;

    int tid = threadIdx.x, lane = tid & 63, w = tid >> 6;
    int px = w & 1, mh = (w >> 1) & 1, nh = (w >> 2) & 1;
    int l15 = lane & 15, g4 = lane >> 4;

    float* outb = out + (size_t)b * 441 * HW + (size_t)y * NW;   // + d*HW + x

    int ilo_h = hf ? 11 : 0, ihi_h = hf ? 20 : 10;
    int ilo   = imax(ilo_h, 10 - uy);
    int ihi   = imin(ihi_h, 33 - uy);

    // gather/zero-fill work item: 336 = 21 j * 16 x-quads; one float4 each
    int gj = tid >> 4, gxq = (tid & 15) << 2;
    bool gact = (tid < ND * 16);

    // zero-fill output rows whose displaced source row is out of bounds
    for (int i = ilo_h; i <= ihi_h; ++i) {
        if (i >= ilo && i <= ihi) continue;
        if (gact) {
            f32x4 z = {0.f, 0.f, 0.f, 0.f};
            *reinterpret_cast<f32x4*>(&outb[(size_t)(i * ND + gj) * HW + gxq]) = z;
        }
    }
    if (ilo > ihi) return;

    // ---- A fragments: coalesced, one-time ----
    const char* ablob = reinterpret_cast<const char*>(ws + ((size_t)(384 + b * 48 + y) << 14));
    int aoff = px * 2048 + mh * 1024 + lane * 16;
    short8 afrag[8];
    #pragma unroll
    for (int kk = 0; kk < 8; ++kk)
        afrag[kk] = *reinterpret_cast<const short8*>(ablob + kk * 4096 + aoff);

    int boff = px * 2048 + nh * 1024 + lane * 16;
    auto loadB = [&](short8* bf, int i) {
        const char* bb = reinterpret_cast<const char*>(
            ws + ((size_t)(b * 48 + 2 * (uy + i - 10) + py) << 14));
        #pragma unroll
        for (int kk = 0; kk < 8; ++kk)
            bf[kk] = *reinterpret_cast<const short8*>(bb + kk * 4096 + boff);
    };

    int srow = 2 * (mh * 16 + g4 * 4) + px;      // + 2*rr
    int scol = nh * 16 + l15;

    short8 bfA[8], bfB[8];
    loadB(bfA, ilo);
    if (ilo + 1 <= ihi) loadB(bfB, ilo + 1);

    int i = ilo;
    while (true) {
        { // ---- phase A: bfA, Sl[0] ----
            f32x4 acc = {0.f, 0.f, 0.f, 0.f};
            #pragma unroll
            for (int kk = 0; kk < 8; ++kk)
                acc = __builtin_amdgcn_mfma_f32_16x16x32_bf16(afrag[kk], bfA[kk], acc, 0, 0, 0);
            if (i + 2 <= ihi) loadB(bfA, i + 2);
            // C/D: col=lane&15 -> vx, row=g4*4+rr -> ux (verified R1-R13)
            // S swizzle: idx = row*32 + ((col+row)&31) -> 2-way (free) both sides
            #pragma unroll
            for (int rr = 0; rr < 4; ++rr) {
                int row = srow + 2 * rr;
                Sl[0][(row << 5) | ((scol + row) & 31)] = acc[rr] * (1.f / 256.f);
            }
            BARRIER();                             // S ready; prev gathers retired
            if (gact) {                            // banded gather, one dwordx4/thread
                f32x4 o4;
                #pragma unroll
                for (int e = 0; e < 4; ++e) {
                    int x  = gxq + e;
                    int vx = (x >> 1) + gj - 10;
                    o4[e] = ((unsigned)vx < 32u) ? Sl[0][(x << 5) | ((vx + x) & 31)] : 0.f;
                }
                *reinterpret_cast<f32x4*>(&outb[(size_t)(i * ND + gj) * HW + gxq]) = o4;
            }
            if (++i > ihi) break;
        }
        { // ---- phase B: bfB, Sl[1] ----
            f32x4 acc = {0.f, 0.f, 0.f, 0.f};
            #pragma unroll
            for (int kk = 0; kk < 8; ++kk)
                acc = __builtin_amdgcn_mfma_f32_16x16x32_bf16(afrag[kk], bfB[kk], acc, 0, 0, 0);
            if (i + 2 <= ihi) loadB(bfB, i + 2);
            #pragma unroll
            for (int rr = 0; rr < 4; ++rr) {
                int row = srow + 2 * rr;
                Sl[1][(row << 5) | ((scol + row) & 31)] = acc[rr] * (1.f / 256.f);
            }
            BARRIER();
            if (gact) {
                f32x4 o4;
                #pragma unroll
                for (int e = 0; e < 4; ++e) {
                    int x  = gxq + e;
                    int vx = (x >> 1) + gj - 10;
                    o4[e] = ((unsigned)vx < 32u) ? Sl[1][(x << 5) | ((vx + x) & 31)] : 0.f;
                }
                *reinterpret_cast<f32x4*>(&outb[(size_t)(i * ND + gj) * HW + gxq]) = o4;
            }
            if (++i > ihi) break;
        }
    }
}

// ============================================================================
// fallback (round-1 structure, known good, no workspace)
// ============================================================================
__device__ __forceinline__ unsigned int swz_off(int row, int cb) {
    return (row << 9) + ((cb << 1) ^ (((row >> 1) & 7) << 4));
}

__device__ __forceinline__ void stage_commit_lds(const Stage& st, unsigned short* lds, int xp, int cg) {
    #pragma unroll
    for (int cc = 0; cc < 2; ++cc) {
        int c0 = cc * 128 + cg * 8;
        u32x4 p0, p1;
        stage_pack(st, cc, p0, p1);
        *reinterpret_cast<u32x4*>(reinterpret_cast<char*>(lds) + swz_off(2 * xp,     c0)) = p0;
        *reinterpret_cast<u32x4*>(reinterpret_cast<char*>(lds) + swz_off(2 * xp + 1, c0)) = p1;
    }
}

__global__ __launch_bounds__(512, 4) void corr_fallback(const float* __restrict__ f1,
                                                        const float* __restrict__ f2,
                                                        float* __restrict__ out) {
    __shared__ __align__(16) unsigned short Alds[64 * 256];
    __shared__ __align__(16) unsigned short Blds[64 * 256];
    __shared__ float Slds[64][33];

    int bid = blockIdx.x;
    int swz = (bid & 7) * 48 + (bid >> 3);
    int uy = swz % 24;
    int g  = swz / 24;
    int py = g & 1;
    int b  = g >> 1;
    int y  = 2 * uy + py;

    int tid = threadIdx.x, lane = tid & 63, w = tid >> 6;
    int xp = tid & 31, cg = tid >> 5;

    const float* f1row  = f1 + (size_t)b * NC * HW + (size_t)y * NW;
    const float* f2base = f2 + (size_t)b * NC * HW;
    float* outb = out + (size_t)b * 441 * HW + (size_t)y * NW;

    for (int i = 0; i < ND; ++i) {
        int vy = uy + i - 10;
        if (vy >= 0 && vy < H2) continue;
        for (int t = tid; t < ND * 64; t += 512) {
            int j = t >> 6, x = t & 63;
            outb[(size_t)(i * ND + j) * HW + x] = 0.f;
        }
    }

    Stage st;
    stage_issue(st, f1row, xp, cg);
    stage_commit_lds(st, Alds, xp, cg);
    __syncthreads();

    int px  = w & 1;
    int m0  = ((w >> 1) & 1) * 16;
    int n0  = ((w >> 2) & 1) * 16;
    int l15 = lane & 15;
    int kgr = (lane >> 4) * 8;

    short8 afrag[8];
    int arow = 2 * (m0 + l15) + px;
    #pragma unroll
    for (int kk = 0; kk < 8; ++kk)
        afrag[kk] = *reinterpret_cast<const short8*>(
            reinterpret_cast<const char*>(Alds) + swz_off(arow, kk * 32 + kgr));

    int brow = 2 * (n0 + l15) + px;
    int srow = 2 * (m0 + (lane >> 4) * 4) + px;
    int scol = n0 + l15;

    for (int vy = uy - 10; vy <= uy + 10; ++vy) {
        if (vy < 0 || vy >= H2) continue;
        int i  = vy - uy + 10;
        int y2 = 2 * vy + py;
        __syncthreads();
        stage_issue(st, f2base + (size_t)y2 * NW, xp, cg);
        stage_commit_lds(st, Blds, xp, cg);
        __syncthreads();

        f32x4 acc = {0.f, 0.f, 0.f, 0.f};
        #pragma unroll
        for (int kk = 0; kk < 8; ++kk) {
            short8 bfrag = *reinterpret_cast<const short8*>(
                reinterpret_cast<const char*>(Blds) + swz_off(brow, kk * 32 + kgr));
            acc = __builtin_amdgcn_mfma_f32_16x16x32_bf16(afrag[kk], bfrag, acc, 0, 0, 0);
        }
        #pragma unroll
        for (int r = 0; r < 4; ++r)
            Slds[srow + 2 * r][scol] = acc[r] * (1.f / 256.f);
        __syncthreads();

        for (int t = tid; t < ND * 64; t += 512) {
            int j = t >> 6, x = t & 63;
            int vx = (x >> 1) + j - 10;
            float v = ((unsigned)vx < 32u) ? Slds[x][vx] : 0.f;
            outb[(size_t)(i * ND + j) * HW + x] = v;
        }
    }
}

extern "C" void kernel_launch(void* const* d_in, const int* in_sizes, int n_in,
                              void* d_out, int out_size, void* d_ws, size_t ws_size,
                              hipStream_t stream) {
    const float* in1 = (const float*)d_in[0];
    const float* in2 = (const float*)d_in[1];
    float* o = (float*)d_out;
    if (ws_size >= WS_FULL) {
        hipLaunchKernelGGL(prep_kernel, dim3(768), dim3(512), 0, stream, in1, in2, (unsigned short*)d_ws);
        hipLaunchKernelGGL(corr_main7, dim3(768), dim3(512), 0, stream,
                           (const unsigned short*)d_ws, o);
    } else {
        hipLaunchKernelGGL(corr_fallback, dim3(384), dim3(512), 0, stream, in1, in2, o);
    }
}